// Round 6
// baseline (53.246 us; speedup 1.0000x reference)
//
#include <hip/hip_runtime.h>
#include <hip/hip_bf16.h>

#define Bdim 4096
#define Ldim 4096
#define Hdim 1024
#define BM 128
#define BN 128
#define BK 64
#define NT (Hdim / BK)   // 16 K-tiles

typedef __attribute__((ext_vector_type(8))) __bf16 bf16x8;
typedef __attribute__((ext_vector_type(4))) float floatx4;

__device__ __forceinline__ unsigned short f2bf(float f) {
  union { __hip_bfloat16 h; unsigned short u; } c;
  c.h = __float2bfloat16(f);
  return c.u;
}

// ---- fused prep: blocks [0,Ldim) do W->bf16 + bias row; [Ldim,+Bdim) X->bf16
__global__ __launch_bounds__(256) void prep_kernel(
    const float* __restrict__ X, const float* __restrict__ E,
    const float* __restrict__ W, const float* __restrict__ b,
    unsigned short* __restrict__ Xb, unsigned short* __restrict__ Wb,
    float* __restrict__ bias) {
  const int blk = blockIdx.x;
  const int t = threadIdx.x;
  if (blk < Ldim) {
    const int row = blk;
    const float4 wv = reinterpret_cast<const float4*>(W + (size_t)row * Hdim)[t];
    const float4 ev = reinterpret_cast<const float4*>(E + (size_t)row * Hdim)[t];
    ushort4 o;
    o.x = f2bf(wv.x); o.y = f2bf(wv.y); o.z = f2bf(wv.z); o.w = f2bf(wv.w);
    reinterpret_cast<ushort4*>(Wb + (size_t)row * Hdim)[t] = o;
    float dot = wv.x * ev.x + wv.y * ev.y + wv.z * ev.z + wv.w * ev.w;
#pragma unroll
    for (int off = 32; off > 0; off >>= 1) dot += __shfl_down(dot, off, 64);
    __shared__ float part[4];
    if ((t & 63) == 0) part[t >> 6] = dot;
    __syncthreads();
    if (t == 0) bias[row] = part[0] + part[1] + part[2] + part[3] + b[row];
  } else {
    const int i = (blk - Ldim) * 256 + t;
    float4 v = reinterpret_cast<const float4*>(X)[i];
    ushort4 o;
    o.x = f2bf(v.x); o.y = f2bf(v.y); o.z = f2bf(v.z); o.w = f2bf(v.w);
    reinterpret_cast<ushort4*>(Xb)[i] = o;
  }
}

// ---- C[B,L] = Xb @ Wb^T + bias -----------------------------------------
// R6: 128x128, BK=64, 256 threads (4 waves, 2Mx2N, 64x64 each), LDS 64 KB
// -> TWO resident blocks/CU (R5 post-mortem: with 1 block/CU the barriers
// and the C-write epilogue stall the whole CU; the loop itself is only
// ~5-7us of LDS/MFMA). Grid 1024 = 4 rounds of blocks: epilogue overlaps
// the co-resident block's loop and the next block's prologue.
// Schedule = R5's verified 4-phase cadence, counts halved:
//   P0: [stage Bh0(t+1)->o] reads A(0..1)+B(0..1); BAR; lgkm0; 8 MFMA
//   P1: [stage Bh1(t+1)->o] reads A(2..3);        BAR; lgkm0; 8 MFMA; BAR
//   P2: [stage Ah0(t+2)->c] reads B(2..3);        BAR; lgkm0; 8 MFMA; BAR
//   P3: [stage Ah1(t+2)->c] GATE vmcnt(4)+BAR;               8 MFMA
// WAR legality (== R5): all af reads complete at P1's post-MFMA barrier ->
// A(t+2) stages into buf c at P2/P3 safe; buf-o B last read at t-1's P2,
// certified by t-1 P3's gate barrier -> P0/P1 B-stages safe.
// Gate accounting: at P3, outstanding = A(t+1)[4]+B(t+1)[4]+A(t+2)[4]=12;
// vmcnt(4) retires all of t+1, leaves A(t+2) in flight. Tile 14: A(15)[4]+
// B(15)[4] -> GATE0. Tile 15: no stage/gate. Never vmcnt(0) mid-loop.
// LDS swizzle (T2, conflicts=0 measured R1/R2/R5): 16B-slot ks of row r at
// ks ^ (r&7); GLL dest linear, global SOURCE pre-swizzled (row == tid>>3
// mod 8 under the GLL lane pattern), reads apply the same XOR.
// XCD chunk (bijective, 1024=8x128): XCD x owns M-rows [4x,4x+4) x all N;
// A-panels (4 x 256KB) stay L2-resident, B streams from LLC.
__global__ __launch_bounds__(256, 2) void gemm_bias_kernel(
    const unsigned short* __restrict__ A,   // [Bdim][Hdim] bf16 bits
    const unsigned short* __restrict__ Bw,  // [Ldim][Hdim] bf16 bits
    const float* __restrict__ bias,         // [Ldim]
    float* __restrict__ C) {                // [Bdim][Ldim] fp32
  __shared__ __align__(16) unsigned short lds[2][2][BM * BK];  // 64 KB

  const int tid = threadIdx.x;
  const int lane = tid & 63;
  const int wave = tid >> 6;
  const int wm = wave >> 1;   // 0..1 (M half, 64 rows)
  const int wn = wave & 1;    // 0..1 (N half, 64 cols)

  // XCD-chunked bijective swizzle (1024 % 8 == 0)
  const int bid = blockIdx.x;
  const int xcd = bid & 7;
  const int idx = bid >> 3;                    // 0..127
  const int m_blk = (xcd * 4 + (idx >> 5)) * BM;
  const int n_blk = (idx & 31) * BN;

  // staging source (pre-swizzled): thread covers row tid>>3, 16B-slot tid&7
  const int srow = tid >> 3;                   // 0..31
  const int skofs = ((tid & 7) ^ ((tid >> 3) & 7)) * 8;
  const unsigned short* gA = A + (size_t)(m_blk + srow) * Hdim + skofs;
  const unsigned short* gB = Bw + (size_t)(n_blk + srow) * Hdim + skofs;

  // fragment read offsets (swizzled): row = base+fr, k 16B-slot = ksl*4+fq
  const int fr = lane & 15;
  const int fq = lane >> 4;
  const int kx0 = ((fq) ^ (fr & 7)) * 8;       // k 0..31
  const int kx1 = ((4 + fq) ^ (fr & 7)) * 8;   // k 32..63
  const int aBase = (wm * 64 + fr) * BK;
  const int bBase = (wn * 64 + fr) * BK;

  floatx4 acc[4][4] = {};
  bf16x8 af[4][2], bfv[4][2];

#define GLL(src, dst)                                                  \
  __builtin_amdgcn_global_load_lds(                                    \
      (const __attribute__((address_space(1))) void*)(src),            \
      (__attribute__((address_space(3))) void*)(dst), 16, 0, 0)

  // stage one half-tile (mat 0=A 1=B, h = 64-row half) of K-tile kt into buf c
  // 2 GLL rounds of 32 rows each (256 thr x 16B = 4 KB = 32 rows x 128 B)
#define STAGE_H(c, mat, h, kt)                                         \
  do {                                                                 \
    const unsigned short* _g = (mat) ? gB : gA;                        \
    GLL(_g + (size_t)((h) * 64) * Hdim + (size_t)(kt) * BK,            \
        &lds[c][mat][(h) * 4096 + tid * 8]);                           \
    GLL(_g + (size_t)((h) * 64 + 32) * Hdim + (size_t)(kt) * BK,       \
        &lds[c][mat][(h) * 4096 + 2048 + tid * 8]);                    \
  } while (0)

#define READ_A(c, lo)                                                  \
  do {                                                                 \
    _Pragma("unroll") for (int mi = (lo); mi < (lo) + 2; ++mi) {       \
      af[mi][0] = *(const bf16x8*)&lds[c][0][aBase + mi * 16 * BK + kx0]; \
      af[mi][1] = *(const bf16x8*)&lds[c][0][aBase + mi * 16 * BK + kx1]; \
    }                                                                  \
  } while (0)

#define READ_B(c, lo)                                                  \
  do {                                                                 \
    _Pragma("unroll") for (int ni = (lo); ni < (lo) + 2; ++ni) {       \
      bfv[ni][0] = *(const bf16x8*)&lds[c][1][bBase + ni * 16 * BK + kx0]; \
      bfv[ni][1] = *(const bf16x8*)&lds[c][1][bBase + ni * 16 * BK + kx1]; \
    }                                                                  \
  } while (0)

  // one C-quadrant (2 mi x 2 ni x 2 ksl = 8 MFMA), setprio-wrapped (T5)
#define MFMA_Q(M0, N0)                                                 \
  do {                                                                 \
    __builtin_amdgcn_s_setprio(1);                                     \
    _Pragma("unroll") for (int mi = (M0); mi < (M0) + 2; ++mi)         \
      _Pragma("unroll") for (int ni = (N0); ni < (N0) + 2; ++ni) {     \
        acc[mi][ni] = __builtin_amdgcn_mfma_f32_16x16x32_bf16(         \
            af[mi][0], bfv[ni][0], acc[mi][ni], 0, 0, 0);              \
        acc[mi][ni] = __builtin_amdgcn_mfma_f32_16x16x32_bf16(         \
            af[mi][1], bfv[ni][1], acc[mi][ni], 0, 0, 0);              \
      }                                                                \
    __builtin_amdgcn_s_setprio(0);                                     \
  } while (0)

#define BAR __builtin_amdgcn_s_barrier()
#define LGKM0 asm volatile("s_waitcnt lgkmcnt(0)" ::: "memory")
#define GATE4 asm volatile("s_waitcnt vmcnt(4)\n\ts_barrier" ::: "memory")
#define GATE0 asm volatile("s_waitcnt vmcnt(0)\n\ts_barrier" ::: "memory")

  // DO_B: stage B(kt+1)->o at P0/P1.  DO_A: stage A(kt+2)->c at P2/P3.
#define TILE_BODY(c, o, kt, DO_B, DO_A, GATE)                          \
  do {                                                                 \
    /* P0 */                                                           \
    if (DO_B) STAGE_H(o, 1, 0, (kt) + 1);                              \
    READ_A(c, 0);                                                      \
    READ_B(c, 0);                                                      \
    BAR; LGKM0;                                                        \
    MFMA_Q(0, 0);                                                      \
    /* P1 */                                                           \
    if (DO_B) STAGE_H(o, 1, 1, (kt) + 1);                              \
    READ_A(c, 2);                                                      \
    BAR; LGKM0;                                                        \
    MFMA_Q(2, 0);                                                      \
    BAR;  /* collective: all af reads of buf c complete -> c.A free */ \
    /* P2 */                                                           \
    if (DO_A) STAGE_H(c, 0, 0, (kt) + 2);                              \
    READ_B(c, 2);                                                      \
    BAR; LGKM0;                                                        \
    MFMA_Q(0, 2);                                                      \
    BAR;  /* collective: all reads of buf c complete */                \
    /* P3 */                                                           \
    if (DO_A) STAGE_H(c, 0, 1, (kt) + 2);                              \
    GATE;                                                              \
    MFMA_Q(2, 2);                                                      \
  } while (0)

  // prologue: tile 0 fully (8 GLL) + tile 1 A halves (4 GLL); gate to 4
  STAGE_H(0, 0, 0, 0);
  STAGE_H(0, 0, 1, 0);
  STAGE_H(0, 1, 0, 0);
  STAGE_H(0, 1, 1, 0);
  STAGE_H(1, 0, 0, 1);
  STAGE_H(1, 0, 1, 1);
  GATE4;

#pragma unroll 1
  for (int t = 0; t < NT - 2; t += 2) {
    TILE_BODY(0, 1, t, 1, 1, GATE4);
    TILE_BODY(1, 0, t + 1, 1, 1, GATE4);
  }
  // tile NT-2 (buf 0): stages B(NT-1)->buf1 (R4-bugfix coverage); no A
  // stage; GATE0 drains A(15)+B(15) (B(15) issued 2 phases earlier).
  TILE_BODY(0, 1, NT - 2, 1, 0, GATE0);
  // tile NT-1 (buf 1): all data resident & retired; no stages, no gate.
  TILE_BODY(1, 0, NT - 1, 0, 0, (void)0);

#undef GLL
#undef STAGE_H
#undef READ_A
#undef READ_B
#undef MFMA_Q
#undef BAR
#undef LGKM0
#undef GATE4
#undef GATE0
#undef TILE_BODY

  // epilogue: C/D layout col=lane&15, row=(lane>>4)*4+reg  [m89-verified]
  const int col0 = n_blk + wn * 64 + fr;
  const int row0 = m_blk + wm * 64 + fq * 4;
#pragma unroll
  for (int ni = 0; ni < 4; ++ni) {
    const float bs = bias[col0 + ni * 16];
#pragma unroll
    for (int mi = 0; mi < 4; ++mi) {
      float* cp = C + (size_t)(row0 + mi * 16) * Ldim + (col0 + ni * 16);
      floatx4 v = acc[mi][ni];
      cp[0 * (size_t)Ldim] = v.x + bs;
      cp[1 * (size_t)Ldim] = v.y + bs;
      cp[2 * (size_t)Ldim] = v.z + bs;
      cp[3 * (size_t)Ldim] = v.w + bs;
    }
  }
}

extern "C" void kernel_launch(void* const* d_in, const int* in_sizes, int n_in,
                              void* d_out, int out_size, void* d_ws, size_t ws_size,
                              hipStream_t stream) {
  const float* X = (const float*)d_in[0];  // bert_output [B,H]
  const float* E = (const float*)d_in[1];  // label_embed [L,H]
  const float* W = (const float*)d_in[2];  // W [L,H]
  const float* b = (const float*)d_in[3];  // b [L]
  // d_in[4] = labels, unused by the reference output.
  float* out = (float*)d_out;

  unsigned short* Xb = (unsigned short*)d_ws;                 // 8 MB
  unsigned short* Wb = Xb + (size_t)Bdim * Hdim;              // 8 MB
  float* bias = (float*)(Wb + (size_t)Ldim * Hdim);           // 16 KB

  prep_kernel<<<Ldim + Bdim, 256, 0, stream>>>(X, E, W, b, Xb, Wb, bias);
  gemm_bias_kernel<<<(Bdim / BM) * (Ldim / BN), 256, 0, stream>>>(Xb, Wb, bias, out);
}